// Round 16
// baseline (377.614 us; speedup 1.0000x reference)
//
#include <hip/hip_runtime.h>

#define HH 256
#define WW 256
#define CC 64
#define FF 128
#define NN 8
#define OUTC 384           // 3*C sep + C lap + F learned
#define HW (HH * WW)

typedef __attribute__((ext_vector_type(8))) short bf16x8;
typedef __attribute__((ext_vector_type(4))) float f32x4;

__device__ __forceinline__ int clampi(int v, int lo, int hi) {
    return v < lo ? lo : (v > hi ? hi : v);
}

// round-to-nearest-even fp32 -> bf16
static __device__ __forceinline__ unsigned short f2bf(float x) {
    unsigned u = __builtin_bit_cast(unsigned, x);
    u += 0x7FFFu + ((u >> 16) & 1u);
    return (unsigned short)(u >> 16);
}
static __device__ __forceinline__ unsigned packbf(float a, float b) {
    return (unsigned)f2bf(a) | ((unsigned)f2bf(b) << 16);
}
static __device__ __forceinline__ float bf2f(unsigned short s) {
    return __builtin_bit_cast(float, (unsigned)s << 16);
}
static __device__ __forceinline__ void nts4(float* p, float a, float b, float c, float d) {
    f32x4 v = {a, b, c, d};
    __builtin_nontemporal_store(v, reinterpret_cast<f32x4*>(p));
}

// ---------------------------------------------------------------------------
// k0: prep = pack (16384 blocks) + wT (36 blocks) merged in one grid.
//  pack: x NCHW fp32 -> xt NC8HW8 bf16: xt[n][cg][h][w][8ch].
//  wT:   W[f][c][3][3] fp32 -> wsW bf16 [t][kg][f][8ch] (147456 B).
// ---------------------------------------------------------------------------
__global__ __launch_bounds__(256) void prep_kernel(const float* __restrict__ x,
                                                   const float* __restrict__ Wl,
                                                   unsigned short* __restrict__ xt,
                                                   unsigned short* __restrict__ wsW) {
    int b = blockIdx.x;
    if (b >= 16384) {
        // ---- wT ----
        int e = (b - 16384) * 256 + threadIdx.x;    // (t, kg, f): 9*8*128 = 9216
        if (e >= 9216) return;
        int t = e >> 10;
        int rem = e & 1023;
        int kg = rem >> 7;
        int f = rem & 127;
        unsigned u[4];
#pragma unroll
        for (int j2 = 0; j2 < 4; ++j2) {
            float a = Wl[(size_t)f * 576 + (size_t)(kg * 8 + 2 * j2) * 9 + t];
            float bq = Wl[(size_t)f * 576 + (size_t)(kg * 8 + 2 * j2 + 1) * 9 + t];
            u[j2] = packbf(a, bq);
        }
        *reinterpret_cast<uint4*>(wsW + (size_t)e * 8) = make_uint4(u[0], u[1], u[2], u[3]);
        return;
    }
    // ---- pack ----
    int y = b & 255;
    int cg = (b >> 8) & 7;
    int n = b >> 11;
    int w = threadIdx.x;
    const float* xp = x + ((size_t)(n * CC + cg * 8)) * HW + (size_t)y * WW + w;
    unsigned u[4];
#pragma unroll
    for (int j2 = 0; j2 < 4; ++j2)
        u[j2] = packbf(xp[(size_t)(2 * j2) * HW], xp[(size_t)(2 * j2 + 1) * HW]);
    *reinterpret_cast<uint4*>(xt + ((size_t)((n * 8 + cg) * HH + y) * WW + w) * 8) =
        make_uint4(u[0], u[1], u[2], u[3]);
}

// ---------------------------------------------------------------------------
// k1: MIXED block-specialized kernel, 24576 blocks x 256 thr, interleave 1:2.
//  r==0 -> learned block: 64f x 128px MFMA; wave = 32f x 64px, acc[2][4]
//          (32 VGPR acc -> whole kernel <=64 VGPR -> 32 waves/CU, 2x the
//          latency hiding of the R12 acc[4][4] variant).
//  r>=1 -> dw block: (n,cg,y), 8ch x 256px, 4 fixed filters, 1 row.
// launch_bounds(256,8) pins VGPR<=64 for BOTH species (single-kernel
// allocation is max-species). Per-XCD dense counters keep n=xcd, y
// sequential -> xt windows L2-hot. All out stores nontemporal (R10).
// ---------------------------------------------------------------------------
__global__ __launch_bounds__(256, 8) void mixed_kernel(const unsigned short* __restrict__ wsW,
                                                       const unsigned short* __restrict__ xt,
                                                       const float* __restrict__ bl,
                                                       float* __restrict__ out) {
    __shared__ float lds_e[4][16][68];        // 17408 B, per-wave slabs (learned)

    int b = blockIdx.x;
    int xcd = b & 7;
    int g = b >> 3;                           // 0..3071
    int r = g % 3;
    int cnt = g / 3;                          // dense 0..1023 per (xcd, r)
    int n = xcd;

    if (r == 0) {
        // ================= learned block: 64f x 128px =================
        int y = cnt >> 2;                     // 0..255
        int sub = cnt & 3;
        int xs = sub >> 1;                    // px 128-half of the row
        int fh = sub & 1;                     // f 64-half

        int tid = threadIdx.x;
        int lane = tid & 63;
        int w = tid >> 6;
        int wf = w >> 1;                      // 32f-half within the 64f (0..1)
        int ws = w & 1;                       // px 64-segment (0..1)
        int x0 = xs * 128 + ws * 64;
        int fb = fh * 64 + wf * 32;           // wave's f base
        int lr = lane & 15;
        int lk = lane >> 4;

        const char* xb = reinterpret_cast<const char*>(xt) + (size_t)n * (8 * HH * WW * 16);

        f32x4 acc[2][4] = {};                 // [mt (16f tile)][j (16px group)]

#pragma unroll
        for (int t = 0; t < 9; ++t) {
            int dy = t / 3, dx = t - 3 * (t / 3);
            int yc = clampi(y + dy - 1, 0, HH - 1);
            int colb[4];
#pragma unroll
            for (int j = 0; j < 4; ++j)
                colb[j] = clampi(x0 + j * 16 + lr + dx - 1, 0, WW - 1) * 16;
#pragma unroll
            for (int kk = 0; kk < 2; ++kk) {
                int kg = kk * 4 + lk;
                size_t rowoff = ((size_t)kg * HH + yc) * (WW * 16);
                bf16x8 a4[2], b4[4];
#pragma unroll
                for (int mt = 0; mt < 2; ++mt)
                    a4[mt] = *reinterpret_cast<const bf16x8*>(
                        wsW + ((size_t)(t * 8 + kg) * 128 + fb + mt * 16 + lr) * 8);
#pragma unroll
                for (int j = 0; j < 4; ++j)
                    b4[j] = *reinterpret_cast<const bf16x8*>(xb + rowoff + colb[j]);
#pragma unroll
                for (int mt = 0; mt < 2; ++mt)
#pragma unroll
                    for (int j = 0; j < 4; ++j)
                        acc[mt][j] = __builtin_amdgcn_mfma_f32_16x16x32_bf16(
                            a4[mt], b4[j], acc[mt][j], 0, 0, 0);
            }
        }

        // epilogue: per-wave transpose via private LDS slab; 256B nt stores
        float* le = &lds_e[w][0][0];
#pragma unroll
        for (int mt = 0; mt < 2; ++mt) {
#pragma unroll
            for (int i = 0; i < 4; ++i) {
                int f16 = lk * 4 + i;
                float bv = bl[fb + mt * 16 + f16];
#pragma unroll
                for (int j = 0; j < 4; ++j)
                    le[f16 * 68 + j * 16 + lr] = acc[mt][j][i] + bv;
            }
#pragma unroll
            for (int p = 0; p < 4; ++p) {
                int f16 = p * 4 + lk;
                const float* s = &le[f16 * 68 + lr * 4];
                int f = fb + mt * 16 + f16;
                nts4(out + (size_t)(n * OUTC + 256 + f) * HW + (size_t)y * WW + x0 + lr * 4,
                     s[0], s[1], s[2], s[3]);
            }
        }
        return;
    }

    // ================= dw block =================
    {
        int m = (r - 1) * 1024 + cnt;         // dense 0..2047 per xcd
        int cg = m >> 8;
        int y = m & 255;
        int w = threadIdx.x;

        const unsigned short* xg = xt + (size_t)(n * 8 + cg) * HH * WW * 8;
        int yr[3], wc[3];
#pragma unroll
        for (int d = 0; d < 3; ++d) {
            yr[d] = clampi(y + d - 1, 0, HH - 1);
            wc[d] = clampi(w + d - 1, 0, WW - 1);
        }
        uint4 chunk[3][3];
#pragma unroll
        for (int rr = 0; rr < 3; ++rr)
#pragma unroll
            for (int c = 0; c < 3; ++c)
                chunk[rr][c] = *reinterpret_cast<const uint4*>(
                    xg + ((size_t)yr[rr] * WW + wc[c]) * 8);

        size_t ob = (size_t)n * OUTC * HW + (size_t)y * WW + w;
#pragma unroll
        for (int j = 0; j < 8; ++j) {
            float v[3][3];
#pragma unroll
            for (int rr = 0; rr < 3; ++rr)
#pragma unroll
                for (int c = 0; c < 3; ++c) {
                    unsigned word = (&chunk[rr][c].x)[j >> 1];
                    v[rr][c] = bf2f((unsigned short)(j & 1 ? word >> 16 : word & 0xffff));
                }
            int ch = cg * 8 + j;
            float tL = v[0][0], tC = v[0][1], tR = v[0][2];
            float mL = v[1][0], mC = v[1][1], mR = v[1][2];
            float bL = v[2][0], bC = v[2][1], bR = v[2][2];
            float o0 = mC;
            float o1 = (tL + 2.f * tC + tR) - (bL + 2.f * bC + bR);
            float o2 = (tL - tR) + 2.f * (mL - mR) + (bL - bR);
            float o3 = 4.f * mC - tC - bC - mL - mR;
            __builtin_nontemporal_store(o0, out + ob + (size_t)(ch * 3 + 0) * HW);
            __builtin_nontemporal_store(o1, out + ob + (size_t)(ch * 3 + 1) * HW);
            __builtin_nontemporal_store(o2, out + ob + (size_t)(ch * 3 + 2) * HW);
            __builtin_nontemporal_store(o3, out + ob + (size_t)(192 + ch) * HW);
        }
    }
}

extern "C" void kernel_launch(void* const* d_in, const int* in_sizes, int n_in,
                              void* d_out, int out_size, void* d_ws, size_t ws_size,
                              hipStream_t stream) {
    const float* x  = (const float*)d_in[0];
    const float* Wl = (const float*)d_in[1];
    const float* bl = (const float*)d_in[2];
    float* out = (float*)d_out;

    unsigned short* wsW = (unsigned short*)d_ws;                            // 147456 B
    unsigned short* xt  = (unsigned short*)((char*)d_ws + 262144);          // 64 MB

    prep_kernel<<<16420, 256, 0, stream>>>(x, Wl, xt, wsW);
    mixed_kernel<<<24576, 256, 0, stream>>>(wsW, xt, bl, out);
}

// Round 17
// 231.079 us; speedup vs baseline: 1.6341x; 1.6341x over previous
//
#include <hip/hip_runtime.h>

#define HH 256
#define WW 256
#define CC 64
#define FF 128
#define NN 8
#define OUTC 384           // 3*C sep + C lap + F learned
#define HW (HH * WW)

typedef __attribute__((ext_vector_type(8))) short bf16x8;
typedef __attribute__((ext_vector_type(4))) float f32x4;

__device__ __forceinline__ int clampi(int v, int lo, int hi) {
    return v < lo ? lo : (v > hi ? hi : v);
}

// round-to-nearest-even fp32 -> bf16
static __device__ __forceinline__ unsigned short f2bf(float x) {
    unsigned u = __builtin_bit_cast(unsigned, x);
    u += 0x7FFFu + ((u >> 16) & 1u);
    return (unsigned short)(u >> 16);
}
static __device__ __forceinline__ unsigned packbf(float a, float b) {
    return (unsigned)f2bf(a) | ((unsigned)f2bf(b) << 16);
}
static __device__ __forceinline__ float bf2f(unsigned short s) {
    return __builtin_bit_cast(float, (unsigned)s << 16);
}
static __device__ __forceinline__ void nts4(float* p, float a, float b, float c, float d) {
    f32x4 v = {a, b, c, d};
    __builtin_nontemporal_store(v, reinterpret_cast<f32x4*>(p));
}

// ---------------------------------------------------------------------------
// k0: prep = pack (16384 blocks) + wT (36 blocks) merged in one grid.
//  pack: x NCHW fp32 -> xt NC8HW8 bf16: xt[n][cg][h][w][8ch].
//  wT:   W[f][c][3][3] fp32 -> wsW bf16 [t][kg][f][8ch] (147456 B).
// ---------------------------------------------------------------------------
__global__ __launch_bounds__(256) void prep_kernel(const float* __restrict__ x,
                                                   const float* __restrict__ Wl,
                                                   unsigned short* __restrict__ xt,
                                                   unsigned short* __restrict__ wsW) {
    int b = blockIdx.x;
    if (b >= 16384) {
        // ---- wT ----
        int e = (b - 16384) * 256 + threadIdx.x;    // (t, kg, f): 9*8*128 = 9216
        if (e >= 9216) return;
        int t = e >> 10;
        int rem = e & 1023;
        int kg = rem >> 7;
        int f = rem & 127;
        unsigned u[4];
#pragma unroll
        for (int j2 = 0; j2 < 4; ++j2) {
            float a = Wl[(size_t)f * 576 + (size_t)(kg * 8 + 2 * j2) * 9 + t];
            float bq = Wl[(size_t)f * 576 + (size_t)(kg * 8 + 2 * j2 + 1) * 9 + t];
            u[j2] = packbf(a, bq);
        }
        *reinterpret_cast<uint4*>(wsW + (size_t)e * 8) = make_uint4(u[0], u[1], u[2], u[3]);
        return;
    }
    // ---- pack ----
    int y = b & 255;
    int cg = (b >> 8) & 7;
    int n = b >> 11;
    int w = threadIdx.x;
    const float* xp = x + ((size_t)(n * CC + cg * 8)) * HW + (size_t)y * WW + w;
    unsigned u[4];
#pragma unroll
    for (int j2 = 0; j2 < 4; ++j2)
        u[j2] = packbf(xp[(size_t)(2 * j2) * HW], xp[(size_t)(2 * j2 + 1) * HW]);
    *reinterpret_cast<uint4*>(xt + ((size_t)((n * 8 + cg) * HH + y) * WW + w) * 8) =
        make_uint4(u[0], u[1], u[2], u[3]);
}

// ---------------------------------------------------------------------------
// k1: MIXED block-specialized kernel (R12 optimum, byte-identical body),
// 20480 blocks x 256 thr, interleave 1:4.
//  b%5==0 -> learned block: 128px x 128f MFMA, no staging/barriers.
//  b%5>=1 -> dw block: (n,cg,y), 8ch x 256px, 4 fixed filters, 1 row.
// dw waves keep VMEM/HBM-write busy while learned waves stall on L2 loads.
// Per-XCD dense counters (xcd = bid&7) keep image n = xcd and y sequential
// on each XCD -> xt windows stay L2-hot for both paths.
// All out stores nontemporal (R10: regular stores -50% via cache pollution).
// ---------------------------------------------------------------------------
__global__ __launch_bounds__(256, 4) void mixed_kernel(const unsigned short* __restrict__ wsW,
                                                       const unsigned short* __restrict__ xt,
                                                       const float* __restrict__ bl,
                                                       float* __restrict__ out) {
    __shared__ float lds_e[4][16][68];        // 17408 B, per-wave slabs (learned)

    int b = blockIdx.x;
    int g = b / 5;
    int r = b - g * 5;
    int xcd = b & 7;
    int cnt = g >> 3;                         // dense 0..511 per (r, xcd)

    if (r == 0) {
        // ================= learned block =================
        int n = xcd;
        int y = cnt >> 1;
        int xs = cnt & 1;

        int tid = threadIdx.x;
        int lane = tid & 63;
        int w = tid >> 6;
        int wf = w >> 1;                      // f-half (0..1)
        int ws = w & 1;                       // px 64-segment (0..1)
        int x0 = xs * 128 + ws * 64;
        int lr = lane & 15;
        int lk = lane >> 4;

        const char* xb = reinterpret_cast<const char*>(xt) + (size_t)n * (8 * HH * WW * 16);

        int colb[4][3];
#pragma unroll
        for (int j = 0; j < 4; ++j)
#pragma unroll
            for (int dx = 0; dx < 3; ++dx)
                colb[j][dx] = clampi(x0 + j * 16 + lr + dx - 1, 0, WW - 1) * 16;

        f32x4 acc[4][4] = {};                 // [mt (16f tile)][j (16px group)]

#pragma unroll
        for (int t = 0; t < 9; ++t) {
            int dy = t / 3, dx = t - 3 * (t / 3);
            int yc = clampi(y + dy - 1, 0, HH - 1);
#pragma unroll
            for (int kk = 0; kk < 2; ++kk) {
                int kg = kk * 4 + lk;
                size_t rowoff = ((size_t)kg * HH + yc) * (WW * 16);
                bf16x8 a4[4], b4[4];
#pragma unroll
                for (int mt = 0; mt < 4; ++mt)
                    a4[mt] = *reinterpret_cast<const bf16x8*>(
                        wsW + ((size_t)(t * 8 + kg) * 128 + wf * 64 + mt * 16 + lr) * 8);
#pragma unroll
                for (int j = 0; j < 4; ++j)
                    b4[j] = *reinterpret_cast<const bf16x8*>(xb + rowoff + colb[j][dx]);
#pragma unroll
                for (int mt = 0; mt < 4; ++mt)
#pragma unroll
                    for (int j = 0; j < 4; ++j)
                        acc[mt][j] = __builtin_amdgcn_mfma_f32_16x16x32_bf16(
                            a4[mt], b4[j], acc[mt][j], 0, 0, 0);
            }
        }

        // epilogue: per-wave transpose via private LDS slab; 256B nt stores
        float* le = &lds_e[w][0][0];
#pragma unroll
        for (int mt = 0; mt < 4; ++mt) {
#pragma unroll
            for (int i = 0; i < 4; ++i) {
                int f16 = lk * 4 + i;
                float bv = bl[wf * 64 + mt * 16 + f16];
#pragma unroll
                for (int j = 0; j < 4; ++j)
                    le[f16 * 68 + j * 16 + lr] = acc[mt][j][i] + bv;
            }
#pragma unroll
            for (int p = 0; p < 4; ++p) {
                int f16 = p * 4 + lk;
                const float* s = &le[f16 * 68 + lr * 4];
                int f = wf * 64 + mt * 16 + f16;
                nts4(out + (size_t)(n * OUTC + 256 + f) * HW + (size_t)y * WW + x0 + lr * 4,
                     s[0], s[1], s[2], s[3]);
            }
        }
        return;
    }

    // ================= dw block =================
    {
        int m = (r - 1) * 512 + cnt;          // dense 0..2047 per xcd
        int n = xcd;
        int cg = m >> 8;
        int y = m & 255;
        int w = threadIdx.x;

        const unsigned short* xg = xt + (size_t)(n * 8 + cg) * HH * WW * 8;
        int yr[3], wc[3];
#pragma unroll
        for (int d = 0; d < 3; ++d) {
            yr[d] = clampi(y + d - 1, 0, HH - 1);
            wc[d] = clampi(w + d - 1, 0, WW - 1);
        }
        uint4 chunk[3][3];
#pragma unroll
        for (int rr = 0; rr < 3; ++rr)
#pragma unroll
            for (int c = 0; c < 3; ++c)
                chunk[rr][c] = *reinterpret_cast<const uint4*>(
                    xg + ((size_t)yr[rr] * WW + wc[c]) * 8);

        size_t ob = (size_t)n * OUTC * HW + (size_t)y * WW + w;
#pragma unroll
        for (int j = 0; j < 8; ++j) {
            float v[3][3];
#pragma unroll
            for (int rr = 0; rr < 3; ++rr)
#pragma unroll
                for (int c = 0; c < 3; ++c) {
                    unsigned word = (&chunk[rr][c].x)[j >> 1];
                    v[rr][c] = bf2f((unsigned short)(j & 1 ? word >> 16 : word & 0xffff));
                }
            int ch = cg * 8 + j;
            float tL = v[0][0], tC = v[0][1], tR = v[0][2];
            float mL = v[1][0], mC = v[1][1], mR = v[1][2];
            float bL = v[2][0], bC = v[2][1], bR = v[2][2];
            float o0 = mC;
            float o1 = (tL + 2.f * tC + tR) - (bL + 2.f * bC + bR);
            float o2 = (tL - tR) + 2.f * (mL - mR) + (bL - bR);
            float o3 = 4.f * mC - tC - bC - mL - mR;
            __builtin_nontemporal_store(o0, out + ob + (size_t)(ch * 3 + 0) * HW);
            __builtin_nontemporal_store(o1, out + ob + (size_t)(ch * 3 + 1) * HW);
            __builtin_nontemporal_store(o2, out + ob + (size_t)(ch * 3 + 2) * HW);
            __builtin_nontemporal_store(o3, out + ob + (size_t)(192 + ch) * HW);
        }
    }
}

extern "C" void kernel_launch(void* const* d_in, const int* in_sizes, int n_in,
                              void* d_out, int out_size, void* d_ws, size_t ws_size,
                              hipStream_t stream) {
    const float* x  = (const float*)d_in[0];
    const float* Wl = (const float*)d_in[1];
    const float* bl = (const float*)d_in[2];
    float* out = (float*)d_out;

    unsigned short* wsW = (unsigned short*)d_ws;                            // 147456 B
    unsigned short* xt  = (unsigned short*)((char*)d_ws + 262144);          // 64 MB

    prep_kernel<<<16420, 256, 0, stream>>>(x, Wl, xt, wsW);
    mixed_kernel<<<20480, 256, 0, stream>>>(wsW, xt, bl, out);
}